// Round 1
// baseline (1865.718 us; speedup 1.0000x reference)
//
#include <hip/hip_runtime.h>
#include <math.h>

#define CH 512
#define RED 64

// ---------------------------------------------------------------------------
// Kernel 1: per-pixel linear (1x1 conv as GEMM)
// out[b,o,i] = sum_c W[o,c] * x[b,c,i] + bias[o]
// transpose_store != 0  ->  out[b,i,o]
// 64(o) x 64(i) tile, 256 threads, 4x4 micro-tile per thread, c-chunks of 32.
// ---------------------------------------------------------------------------
__global__ __launch_bounds__(256) void qkv_gemm(
    const float* __restrict__ x, const float* __restrict__ W,
    const float* __restrict__ bias, float* __restrict__ out,
    int C, int O, int N, int transpose_store)
{
    __shared__ float sW[32][65];   // [c][o]
    __shared__ float sX[32][65];   // [c][i]
    const int b  = blockIdx.z;
    const int i0 = blockIdx.x * 64;
    const int o0 = blockIdx.y * 64;
    const int t  = threadIdx.x;
    const int tx = t & 15, ty = t >> 4;
    const float* xb = x + (size_t)b * C * N;

    float acc[4][4] = {};
    for (int c0 = 0; c0 < C; c0 += 32) {
        {
            const int c = t & 31, ob = t >> 5;
            #pragma unroll
            for (int r = 0; r < 8; ++r) {
                const int o = ob + r * 8;
                sW[c][o] = W[(size_t)(o0 + o) * C + (c0 + c)];
            }
        }
        {
            const int i = t & 63, cb = t >> 6;
            #pragma unroll
            for (int r = 0; r < 8; ++r) {
                const int c = cb + r * 4;
                sX[c][i] = xb[(size_t)(c0 + c) * N + (i0 + i)];
            }
        }
        __syncthreads();
        #pragma unroll 8
        for (int c = 0; c < 32; ++c) {
            float wv[4], xv[4];
            #pragma unroll
            for (int a = 0; a < 4; ++a) wv[a] = sW[c][ty + 16 * a];
            #pragma unroll
            for (int e = 0; e < 4; ++e) xv[e] = sX[c][tx + 16 * e];
            #pragma unroll
            for (int a = 0; a < 4; ++a)
                #pragma unroll
                for (int e = 0; e < 4; ++e)
                    acc[a][e] = fmaf(wv[a], xv[e], acc[a][e]);
        }
        __syncthreads();
    }
    #pragma unroll
    for (int a = 0; a < 4; ++a) {
        const int o = o0 + ty + 16 * a;
        const float bb = bias[o];
        #pragma unroll
        for (int e = 0; e < 4; ++e) {
            const int i = i0 + tx + 16 * e;
            const float v = acc[a][e] + bb;
            if (transpose_store) out[((size_t)b * N + i) * O + o] = v;
            else                 out[((size_t)b * O + o) * N + i] = v;
        }
    }
}

// ---------------------------------------------------------------------------
// Kernel 2: softmax row stats (max m_i, denom l_i) over energy rows.
// energy[b,i,j] = sum_r q[b,i,r] * k[b,r,j].  Block = (b, 64-query tile).
// ---------------------------------------------------------------------------
__global__ __launch_bounds__(256) void softmax_stats(
    const float* __restrict__ q,   // [B,N,RED]
    const float* __restrict__ k,   // [B,RED,N]
    float* __restrict__ mrow, float* __restrict__ lrow, int N)
{
    __shared__ float sq[64][65];   // [i][r]
    __shared__ float sk[64][65];   // [r][j]
    __shared__ float rm[64][17];
    __shared__ float rl[64][17];
    const int b  = blockIdx.y;
    const int i0 = blockIdx.x * 64;
    const int t  = threadIdx.x;
    const int tx = t & 15, ty = t >> 4;

    {
        const int r = t & 63, ib = t >> 6;
        #pragma unroll
        for (int s = 0; s < 16; ++s) {
            const int i = ib + s * 4;
            sq[i][r] = q[((size_t)b * N + i0 + i) * RED + r];
        }
    }
    float tm[4], tl[4];
    #pragma unroll
    for (int a = 0; a < 4; ++a) { tm[a] = -3.0e38f; tl[a] = 0.f; }

    for (int j0 = 0; j0 < N; j0 += 64) {
        __syncthreads();
        {
            const int j = t & 63, rb = t >> 6;
            #pragma unroll
            for (int s = 0; s < 16; ++s) {
                const int r = rb + s * 4;
                sk[r][j] = k[((size_t)b * RED + r) * N + j0 + j];
            }
        }
        __syncthreads();
        float sv_[4][4] = {};
        #pragma unroll 8
        for (int r = 0; r < 64; ++r) {
            float qa[4], kb[4];
            #pragma unroll
            for (int a = 0; a < 4; ++a) qa[a] = sq[ty + 16 * a][r];
            #pragma unroll
            for (int e = 0; e < 4; ++e) kb[e] = sk[r][tx + 16 * e];
            #pragma unroll
            for (int a = 0; a < 4; ++a)
                #pragma unroll
                for (int e = 0; e < 4; ++e)
                    sv_[a][e] = fmaf(qa[a], kb[e], sv_[a][e]);
        }
        #pragma unroll
        for (int a = 0; a < 4; ++a)
            #pragma unroll
            for (int e = 0; e < 4; ++e) {
                const float s_ = sv_[a][e];
                const float nm = fmaxf(tm[a], s_);
                tl[a] = tl[a] * __expf(tm[a] - nm) + __expf(s_ - nm);
                tm[a] = nm;
            }
    }
    __syncthreads();
    #pragma unroll
    for (int a = 0; a < 4; ++a) { rm[ty + 16 * a][tx] = tm[a]; rl[ty + 16 * a][tx] = tl[a]; }
    __syncthreads();
    if (t < 64) {
        float M = -3.0e38f;
        #pragma unroll
        for (int u = 0; u < 16; ++u) M = fmaxf(M, rm[t][u]);
        float L = 0.f;
        #pragma unroll
        for (int u = 0; u < 16; ++u) L += rl[t][u] * __expf(rm[t][u] - M);
        mrow[(size_t)b * N + i0 + t] = M;
        lrow[(size_t)b * N + i0 + t] = L;
    }
}

// ---------------------------------------------------------------------------
// Kernel 3: out[b,c,i] = sum_j softmax(energy)[b,i,j] * v[b,c,j];
//           y = gamma*out + x  (fused epilogue).
// Block = (b, 32-query tile), all 512 channels. Recomputes s per 64-j chunk
// using precomputed (m,l); vT staged in LDS per 64-channel tile.
// Thread micro-tile: 2 queries x 4 channels per channel-tile -> 64 acc regs.
// ---------------------------------------------------------------------------
__global__ __launch_bounds__(256) void attn_out(
    const float* __restrict__ q,    // [B,N,RED]
    const float* __restrict__ k,    // [B,RED,N]
    const float* __restrict__ vT,   // [B,N,CH]
    const float* __restrict__ mrow, const float* __restrict__ lrow,
    const float* __restrict__ x,    // [B,CH,N]
    const float* __restrict__ gamma,
    float* __restrict__ y, int N)
{
    __shared__ float sq[32][68];    // [i][r]   (stride 68: 16B-aligned rows, no bank stack)
    __shared__ float sk[64][64];    // [r][j]
    __shared__ float sp[32][68];    // [i][j]
    __shared__ float sv[64][64];    // [j][c]
    __shared__ float sep[64][33];   // epilogue transpose buffer [c][i]
    const int b  = blockIdx.y;
    const int i0 = blockIdx.x * 32;
    const int t  = threadIdx.x;
    const int tx = t & 15, ty = t >> 4;

    {
        const int r = t & 63, ib = t >> 6;
        #pragma unroll
        for (int s = 0; s < 8; ++s) {
            const int i = ib + s * 4;
            sq[i][r] = q[((size_t)b * N + i0 + i) * RED + r];
        }
    }
    const float m0  = mrow[(size_t)b * N + i0 + ty];
    const float m1  = mrow[(size_t)b * N + i0 + ty + 16];
    const float il0 = 1.f / lrow[(size_t)b * N + i0 + ty];
    const float il1 = 1.f / lrow[(size_t)b * N + i0 + ty + 16];

    float acc[8][2][4] = {};   // [c-tile][query][channel]

    for (int j0 = 0; j0 < N; j0 += 64) {
        __syncthreads();
        {
            const int j = t & 63, rb = t >> 6;
            #pragma unroll
            for (int s = 0; s < 16; ++s) {
                const int r = rb + s * 4;
                sk[r][j] = k[((size_t)b * RED + r) * N + j0 + j];
            }
        }
        __syncthreads();
        {   // s = q.k for (2 queries) x (4 contiguous j), then p = exp(s-m)/l
            float s0[4] = {}, s1[4] = {};
            #pragma unroll 8
            for (int r = 0; r < 64; ++r) {
                const float q0 = sq[ty][r], q1 = sq[ty + 16][r];
                const float4 kv = *(const float4*)&sk[r][tx * 4];
                s0[0] = fmaf(q0, kv.x, s0[0]); s0[1] = fmaf(q0, kv.y, s0[1]);
                s0[2] = fmaf(q0, kv.z, s0[2]); s0[3] = fmaf(q0, kv.w, s0[3]);
                s1[0] = fmaf(q1, kv.x, s1[0]); s1[1] = fmaf(q1, kv.y, s1[1]);
                s1[2] = fmaf(q1, kv.z, s1[2]); s1[3] = fmaf(q1, kv.w, s1[3]);
            }
            #pragma unroll
            for (int jj = 0; jj < 4; ++jj) {
                sp[ty][tx * 4 + jj]      = __expf(s0[jj] - m0) * il0;
                sp[ty + 16][tx * 4 + jj] = __expf(s1[jj] - m1) * il1;
            }
        }
        __syncthreads();
        #pragma unroll
        for (int ct = 0; ct < 8; ++ct) {
            {
                const int cc = t & 63, jb = t >> 6;
                #pragma unroll
                for (int s = 0; s < 16; ++s) {
                    const int j = jb + s * 4;
                    sv[j][cc] = vT[((size_t)b * N + j0 + j) * CH + ct * 64 + cc];
                }
            }
            __syncthreads();
            #pragma unroll 4
            for (int j = 0; j < 64; ++j) {
                const float4 vv = *(const float4*)&sv[j][tx * 4];
                const float p0 = sp[ty][j], p1 = sp[ty + 16][j];
                acc[ct][0][0] = fmaf(p0, vv.x, acc[ct][0][0]);
                acc[ct][0][1] = fmaf(p0, vv.y, acc[ct][0][1]);
                acc[ct][0][2] = fmaf(p0, vv.z, acc[ct][0][2]);
                acc[ct][0][3] = fmaf(p0, vv.w, acc[ct][0][3]);
                acc[ct][1][0] = fmaf(p1, vv.x, acc[ct][1][0]);
                acc[ct][1][1] = fmaf(p1, vv.y, acc[ct][1][1]);
                acc[ct][1][2] = fmaf(p1, vv.z, acc[ct][1][2]);
                acc[ct][1][3] = fmaf(p1, vv.w, acc[ct][1][3]);
            }
            __syncthreads();
        }
    }

    // Epilogue: transpose each 64-channel tile through LDS, store y = g*out + x
    const float g = gamma[0];
    #pragma unroll
    for (int ct = 0; ct < 8; ++ct) {
        __syncthreads();
        #pragma unroll
        for (int ii = 0; ii < 2; ++ii)
            #pragma unroll
            for (int cc = 0; cc < 4; ++cc)
                sep[tx * 4 + cc][ty + 16 * ii] = acc[ct][ii][cc];
        __syncthreads();
        const int i = t & 31, cb = t >> 5;
        #pragma unroll
        for (int s = 0; s < 8; ++s) {
            const int c = ct * 64 + cb + s * 8;
            const size_t idx = ((size_t)b * CH + c) * N + i0 + i;
            y[idx] = g * sep[cb + s * 8][i] + x[idx];
        }
    }
}

// ---------------------------------------------------------------------------
extern "C" void kernel_launch(void* const* d_in, const int* in_sizes, int n_in,
                              void* d_out, int out_size, void* d_ws, size_t ws_size,
                              hipStream_t stream) {
    const float* x     = (const float*)d_in[0];
    const float* Wq    = (const float*)d_in[1];
    const float* bq    = (const float*)d_in[2];
    const float* Wk    = (const float*)d_in[3];
    const float* bk    = (const float*)d_in[4];
    const float* Wv    = (const float*)d_in[5];
    const float* bv    = (const float*)d_in[6];
    const float* gamma = (const float*)d_in[7];
    float* y = (float*)d_out;

    const int C = CH, R = RED, N = 64 * 64;
    const int B = in_sizes[0] / (C * N);   // = 4

    // Workspace layout (floats): q | k | vT | m | l   (~42 MB total)
    float* ws   = (float*)d_ws;
    float* qB   = ws;
    float* kB   = qB + (size_t)B * N * R;
    float* vTB  = kB + (size_t)B * R * N;
    float* mB   = vTB + (size_t)B * N * C;
    float* lB   = mB + (size_t)B * N;

    // q[b,i,r], k[b,r,j], vT[b,j,c]
    qkv_gemm<<<dim3(N / 64, R / 64, B), 256, 0, stream>>>(x, Wq, bq, qB,  C, R, N, 1);
    qkv_gemm<<<dim3(N / 64, R / 64, B), 256, 0, stream>>>(x, Wk, bk, kB,  C, R, N, 0);
    qkv_gemm<<<dim3(N / 64, C / 64, B), 256, 0, stream>>>(x, Wv, bv, vTB, C, C, N, 1);

    softmax_stats<<<dim3(N / 64, B), 256, 0, stream>>>(qB, kB, mB, lB, N);

    attn_out<<<dim3(N / 32, B), 256, 0, stream>>>(qB, kB, vTB, mB, lB, x, gamma, y, N);
}

// Round 2
// 523.376 us; speedup vs baseline: 3.5648x; 3.5648x over previous
//
#include <hip/hip_runtime.h>
#include <math.h>

#define CH 512
#define RED 64

typedef __attribute__((ext_vector_type(8))) short bf16x8;
typedef __attribute__((ext_vector_type(4))) float f32x4;

static __device__ __forceinline__ short f2bf(float f) {
    union { float f; unsigned u; } v; v.f = f;
    unsigned r = (v.u + 0x7FFF + ((v.u >> 16) & 1)) >> 16;
    return (short)r;
}

// ---------------------------------------------------------------------------
// x f32 [b][c][n] -> xT bf16 [b][n][c].  32x32 tiles.
// ---------------------------------------------------------------------------
__global__ __launch_bounds__(256) void cast_transpose(
    const float* __restrict__ x, short* __restrict__ xT, int N)
{
    __shared__ float sT[32][33];
    const int b = blockIdx.z, n0 = blockIdx.x * 32, c0 = blockIdx.y * 32;
    const int t = threadIdx.x;
    #pragma unroll
    for (int j = 0; j < 4; ++j) {
        const int c = (t >> 5) + 8 * j;
        sT[c][t & 31] = x[((size_t)b * CH + c0 + c) * N + n0 + (t & 31)];
    }
    __syncthreads();
    #pragma unroll
    for (int j = 0; j < 4; ++j) {
        const int n = (t >> 5) + 8 * j;
        xT[((size_t)b * N + n0 + n) * CH + c0 + (t & 31)] = f2bf(sT[t & 31][n]);
    }
}

// ---------------------------------------------------------------------------
// MFMA GEMM: out = xT * W^T + bias.
//   xT bf16 [b][N][512], W f32 [O][512], bias f32 [O]
//   transp=0: out bf16 [b][N][O]     (i-major)
//   transp=1: out bf16 [b][O][N]     (o-major)
// Tile 64(i) x 64(o), K chunks of 64. 256 threads = 4 waves; wave w owns
// 16-row i-strip x all 64 o.
// ---------------------------------------------------------------------------
__global__ __launch_bounds__(256) void mfma_gemm(
    const short* __restrict__ xT, const float* __restrict__ W,
    const float* __restrict__ bias, short* __restrict__ out,
    int N, int O, int transp)
{
    __shared__ short sA[64][72];   // [i][c]
    __shared__ short sB[64][72];   // [o][c]
    const int b = blockIdx.z, i0 = blockIdx.x * 64, o0 = blockIdx.y * 64;
    const int t = threadIdx.x;
    const int lane = t & 63, w = t >> 6;
    const int quad = lane >> 4, l16 = lane & 15;
    const short* xb = xT + ((size_t)b * N + i0) * CH;

    f32x4 acc[4];
    const f32x4 zz = {0.f, 0.f, 0.f, 0.f};
    #pragma unroll
    for (int nt = 0; nt < 4; ++nt) acc[nt] = zz;

    for (int c0 = 0; c0 < CH; c0 += 64) {
        // A: 64 rows x 64 bf16 = 512 x 16B chunks, 2 per thread
        #pragma unroll
        for (int s = 0; s < 2; ++s) {
            const int id = t + s * 256, r = id >> 3, ch = id & 7;
            *(float4*)&sA[r][ch * 8] = *(const float4*)&xb[(size_t)r * CH + c0 + ch * 8];
        }
        // B: 64 rows x 64 f32 = 1024 x 16B chunks, 4 per thread (convert to bf16)
        #pragma unroll
        for (int s = 0; s < 4; ++s) {
            const int id = t + s * 256, r = id >> 4, ch = id & 15;
            const float4 wv = *(const float4*)&W[(size_t)(o0 + r) * CH + c0 + ch * 4];
            uint2 p;
            p.x = (unsigned short)f2bf(wv.x) | ((unsigned)(unsigned short)f2bf(wv.y) << 16);
            p.y = (unsigned short)f2bf(wv.z) | ((unsigned)(unsigned short)f2bf(wv.w) << 16);
            *(uint2*)&sB[r][ch * 4] = p;
        }
        __syncthreads();
        #pragma unroll
        for (int kk = 0; kk < 64; kk += 32) {
            const bf16x8 af = *(const bf16x8*)&sA[w * 16 + l16][kk + quad * 8];
            #pragma unroll
            for (int nt = 0; nt < 4; ++nt) {
                const bf16x8 bfr = *(const bf16x8*)&sB[nt * 16 + l16][kk + quad * 8];
                acc[nt] = __builtin_amdgcn_mfma_f32_16x16x32_bf16(af, bfr, acc[nt], 0, 0, 0);
            }
        }
        __syncthreads();
    }

    // Epilogue: bias, bf16, bounce through LDS (reuse sA) for coalesced stores.
    #pragma unroll
    for (int nt = 0; nt < 4; ++nt) {
        const int o = nt * 16 + l16;
        const float bb = bias[o0 + o];
        #pragma unroll
        for (int r = 0; r < 4; ++r) {
            const int i = w * 16 + quad * 4 + r;
            const short val = f2bf(acc[nt][r] + bb);
            if (transp) sA[o][i] = val; else sA[i][o] = val;
        }
    }
    __syncthreads();
    const int rr = t >> 2, part = t & 3;
    const int4 w0 = *(const int4*)&sA[rr][part * 16];
    const int4 w1 = *(const int4*)&sA[rr][part * 16 + 8];
    if (transp) {
        short* dst = out + ((size_t)b * O + o0 + rr) * N + i0 + part * 16;
        *(int4*)dst = w0; *(int4*)(dst + 8) = w1;
    } else {
        short* dst = out + ((size_t)b * N + i0 + rr) * O + o0 + part * 16;
        *(int4*)dst = w0; *(int4*)(dst + 8) = w1;
    }
}

// ---------------------------------------------------------------------------
// Softmax row stats via MFMA: m_i = max_j S, il_i = 1/sum_j exp(S-m).
// q,kT bf16 [b][N][64]. Block: 4 waves, 64-query tile, j chunks of 64.
// ---------------------------------------------------------------------------
__global__ __launch_bounds__(256) void stats_mfma(
    const short* __restrict__ q, const short* __restrict__ kT,
    float* __restrict__ mrow, float* __restrict__ ilrow, int N)
{
    __shared__ short sQ[64][72];
    __shared__ short sK[64][72];
    const int b = blockIdx.y, i0 = blockIdx.x * 64;
    const int t = threadIdx.x;
    const int lane = t & 63, w = t >> 6;
    const int quad = lane >> 4, l16 = lane & 15;

    #pragma unroll
    for (int s = 0; s < 2; ++s) {
        const int id = t + s * 256, r = id >> 3, ch = id & 7;
        *(float4*)&sQ[r][ch * 8] = *(const float4*)&q[((size_t)b * N + i0 + r) * RED + ch * 8];
    }
    float tm[4], tl[4];
    #pragma unroll
    for (int r = 0; r < 4; ++r) { tm[r] = -3.0e38f; tl[r] = 0.f; }

    for (int j0 = 0; j0 < N; j0 += 64) {
        __syncthreads();
        #pragma unroll
        for (int s = 0; s < 2; ++s) {
            const int id = t + s * 256, r = id >> 3, ch = id & 7;
            *(float4*)&sK[r][ch * 8] = *(const float4*)&kT[((size_t)b * N + j0 + r) * RED + ch * 8];
        }
        __syncthreads();
        f32x4 S[4];
        const f32x4 zz = {0.f, 0.f, 0.f, 0.f};
        #pragma unroll
        for (int nt = 0; nt < 4; ++nt) S[nt] = zz;
        #pragma unroll
        for (int kk = 0; kk < 64; kk += 32) {
            const bf16x8 af = *(const bf16x8*)&sQ[w * 16 + l16][kk + quad * 8];
            #pragma unroll
            for (int nt = 0; nt < 4; ++nt) {
                const bf16x8 bfr = *(const bf16x8*)&sK[nt * 16 + l16][kk + quad * 8];
                S[nt] = __builtin_amdgcn_mfma_f32_16x16x32_bf16(af, bfr, S[nt], 0, 0, 0);
            }
        }
        #pragma unroll
        for (int r = 0; r < 4; ++r) {
            const float mx = fmaxf(fmaxf(S[0][r], S[1][r]), fmaxf(S[2][r], S[3][r]));
            const float nm = fmaxf(tm[r], mx);
            const float sum = __expf(S[0][r] - nm) + __expf(S[1][r] - nm) +
                              __expf(S[2][r] - nm) + __expf(S[3][r] - nm);
            tl[r] = tl[r] * __expf(tm[r] - nm) + sum;
            tm[r] = nm;
        }
    }
    // reduce across the 16 lanes of each quad (they hold disjoint j-columns)
    #pragma unroll
    for (int r = 0; r < 4; ++r) {
        float m = tm[r], l = tl[r];
        #pragma unroll
        for (int off = 1; off < 16; off <<= 1) {
            const float om = __shfl_xor(m, off);
            const float ol = __shfl_xor(l, off);
            const float nm = fmaxf(m, om);
            l = l * __expf(m - nm) + ol * __expf(om - nm);
            m = nm;
        }
        if (l16 == 0) {
            const int i = i0 + w * 16 + quad * 4 + r;
            mrow[(size_t)b * N + i] = m;
            ilrow[(size_t)b * N + i] = 1.0f / l;
        }
    }
}

// ---------------------------------------------------------------------------
// Attention PV via MFMA + fused residual epilogue.
// Block: 512 threads (8 waves), 64 queries x all 512 channels, j chunks of 64.
// wave w: mw=w&3 -> 16-row i-strip; hw=w>>2 -> channel/j half.
// ---------------------------------------------------------------------------
__global__ __launch_bounds__(512) void attn_mfma(
    const short* __restrict__ q,    // [b][N][64]
    const short* __restrict__ kT,   // [b][N][64]
    const short* __restrict__ v2,   // [b][512][N]
    const float* __restrict__ mrow, const float* __restrict__ ilrow,
    const float* __restrict__ x,    // [b][512][N] f32
    const float* __restrict__ gamma,
    float* __restrict__ y, int N)
{
    __shared__ short sQ[64][72];    // [i][r]
    __shared__ short sK[64][72];    // [j][r]
    __shared__ short sP[64][72];    // [i][j]
    __shared__ short sV[256][72];   // [c][j]  (current 256-channel half)
    const int b = blockIdx.y, i0 = blockIdx.x * 64;
    const int t = threadIdx.x;
    const int lane = t & 63, w = t >> 6;
    const int quad = lane >> 4, l16 = lane & 15;
    const int mw = w & 3, hw = w >> 2;

    { const int r = t >> 3, ch = t & 7;
      *(float4*)&sQ[r][ch * 8] = *(const float4*)&q[((size_t)b * N + i0 + r) * RED + ch * 8]; }

    float mreg[4], ilreg[4];
    #pragma unroll
    for (int r = 0; r < 4; ++r) {
        const int i = i0 + mw * 16 + quad * 4 + r;
        mreg[r] = mrow[(size_t)b * N + i];
        ilreg[r] = ilrow[(size_t)b * N + i];
    }

    f32x4 acc[2][8];
    const f32x4 zz = {0.f, 0.f, 0.f, 0.f};
    #pragma unroll
    for (int h = 0; h < 2; ++h)
        #pragma unroll
        for (int nt = 0; nt < 8; ++nt) acc[h][nt] = zz;

    for (int j0 = 0; j0 < N; j0 += 64) {
        __syncthreads();
        { const int r = t >> 3, ch = t & 7;
          *(float4*)&sK[r][ch * 8] = *(const float4*)&kT[((size_t)b * N + j0 + r) * RED + ch * 8]; }
        __syncthreads();
        // S = Q K^T for this wave's 16 x 32 piece; then P = exp(S-m)*il -> sP
        {
            f32x4 S[2]; S[0] = zz; S[1] = zz;
            #pragma unroll
            for (int kk = 0; kk < 64; kk += 32) {
                const bf16x8 af = *(const bf16x8*)&sQ[mw * 16 + l16][kk + quad * 8];
                #pragma unroll
                for (int nt = 0; nt < 2; ++nt) {
                    const bf16x8 bfr = *(const bf16x8*)&sK[hw * 32 + nt * 16 + l16][kk + quad * 8];
                    S[nt] = __builtin_amdgcn_mfma_f32_16x16x32_bf16(af, bfr, S[nt], 0, 0, 0);
                }
            }
            #pragma unroll
            for (int nt = 0; nt < 2; ++nt)
                #pragma unroll
                for (int r = 0; r < 4; ++r) {
                    const float p = __expf(S[nt][r] - mreg[r]) * ilreg[r];
                    sP[mw * 16 + quad * 4 + r][hw * 32 + nt * 16 + l16] = f2bf(p);
                }
        }
        // PV over the two 256-channel halves
        #pragma unroll
        for (int h = 0; h < 2; ++h) {
            __syncthreads();
            #pragma unroll
            for (int s = 0; s < 4; ++s) {
                const int id = t + s * 512, r = id >> 3, ch = id & 7;
                *(float4*)&sV[r][ch * 8] =
                    *(const float4*)&v2[((size_t)b * CH + h * 256 + r) * N + j0 + ch * 8];
            }
            __syncthreads();
            #pragma unroll
            for (int kk = 0; kk < 64; kk += 32) {
                const bf16x8 af = *(const bf16x8*)&sP[mw * 16 + l16][kk + quad * 8];
                #pragma unroll
                for (int nt = 0; nt < 8; ++nt) {
                    const bf16x8 bfr = *(const bf16x8*)&sV[hw * 128 + nt * 16 + l16][kk + quad * 8];
                    acc[h][nt] = __builtin_amdgcn_mfma_f32_16x16x32_bf16(af, bfr, acc[h][nt], 0, 0, 0);
                }
            }
        }
    }

    // Epilogue: y = g*O + x, transposing 128-channel chunks through LDS (reuse sV).
    const float g = gamma[0];
    float (*sep)[68] = (float(*)[68])sV;   // 128 x 68 f32 = 34.8 KB <= sV
    #pragma unroll
    for (int cc = 0; cc < 4; ++cc) {
        __syncthreads();
        if (hw == (cc & 1)) {
            const int h = cc >> 1;
            #pragma unroll
            for (int nt = 0; nt < 8; ++nt)
                #pragma unroll
                for (int r = 0; r < 4; ++r)
                    sep[nt * 16 + l16][mw * 16 + quad * 4 + r] = acc[h][nt][r];
        }
        __syncthreads();
        const int crow = t >> 2, part = t & 3;
        const size_t base = ((size_t)b * CH + cc * 128 + crow) * N + i0 + part * 16;
        #pragma unroll
        for (int u = 0; u < 4; ++u) {
            const float4 xv = *(const float4*)&x[base + u * 4];
            float4 ov;
            ov.x = g * sep[crow][part * 16 + u * 4 + 0] + xv.x;
            ov.y = g * sep[crow][part * 16 + u * 4 + 1] + xv.y;
            ov.z = g * sep[crow][part * 16 + u * 4 + 2] + xv.z;
            ov.w = g * sep[crow][part * 16 + u * 4 + 3] + xv.w;
            *(float4*)&y[base + u * 4] = ov;
        }
    }
}

// ---------------------------------------------------------------------------
extern "C" void kernel_launch(void* const* d_in, const int* in_sizes, int n_in,
                              void* d_out, int out_size, void* d_ws, size_t ws_size,
                              hipStream_t stream) {
    const float* x     = (const float*)d_in[0];
    const float* Wq    = (const float*)d_in[1];
    const float* bq    = (const float*)d_in[2];
    const float* Wk    = (const float*)d_in[3];
    const float* bk    = (const float*)d_in[4];
    const float* Wv    = (const float*)d_in[5];
    const float* bv    = (const float*)d_in[6];
    const float* gamma = (const float*)d_in[7];
    float* y = (float*)d_out;

    const int N = 64 * 64;
    const int B = in_sizes[0] / (CH * N);   // = 4

    // Workspace (bytes): xT 16.8M | q 2.1M | kT 2.1M | v2 16.8M | m 64K | il 64K  ~= 36.1 MB
    char* ws = (char*)d_ws;
    short* xT = (short*)ws;                                   ws += (size_t)B * N * CH * 2;
    short* qB = (short*)ws;                                   ws += (size_t)B * N * RED * 2;
    short* kB = (short*)ws;                                   ws += (size_t)B * N * RED * 2;
    short* v2 = (short*)ws;                                   ws += (size_t)B * CH * N * 2;
    float* mB = (float*)ws;                                   ws += (size_t)B * N * 4;
    float* ilB = (float*)ws;

    cast_transpose<<<dim3(N / 32, CH / 32, B), 256, 0, stream>>>(x, xT, N);

    mfma_gemm<<<dim3(N / 64, RED / 64, B), 256, 0, stream>>>(xT, Wq, bq, qB, N, RED, 0);
    mfma_gemm<<<dim3(N / 64, RED / 64, B), 256, 0, stream>>>(xT, Wk, bk, kB, N, RED, 0);
    mfma_gemm<<<dim3(N / 64, CH / 64, B), 256, 0, stream>>>(xT, Wv, bv, v2, N, CH, 1);

    stats_mfma<<<dim3(N / 64, B), 256, 0, stream>>>(qB, kB, mB, ilB, N);

    attn_mfma<<<dim3(N / 64, B), 512, 0, stream>>>(qB, kB, v2, mB, ilB, x, gamma, y, N);
}

// Round 3
// 336.239 us; speedup vs baseline: 5.5488x; 1.5566x over previous
//
#include <hip/hip_runtime.h>
#include <math.h>

#define CH 512
#define RED 64

typedef __attribute__((ext_vector_type(8))) short bf16x8;
typedef __attribute__((ext_vector_type(4))) float f32x4;

typedef const __attribute__((address_space(1))) void* gas_t;
typedef __attribute__((address_space(3))) void* las_t;

static __device__ __forceinline__ short f2bf(float f) {
    union { float f; unsigned u; } v; v.f = f;
    unsigned r = (v.u + 0x7FFF + ((v.u >> 16) & 1)) >> 16;
    return (short)r;
}

static __device__ __forceinline__ void gl16(const void* g, void* l) {
    __builtin_amdgcn_global_load_lds((gas_t)g, (las_t)l, 16, 0, 0);
}

// ---------------------------------------------------------------------------
// x f32 [b][c][n] -> xT bf16 [b][n][c].  32x32 tiles.
// ---------------------------------------------------------------------------
__global__ __launch_bounds__(256) void cast_transpose(
    const float* __restrict__ x, short* __restrict__ xT, int N)
{
    __shared__ float sT[32][33];
    const int b = blockIdx.z, n0 = blockIdx.x * 32, c0 = blockIdx.y * 32;
    const int t = threadIdx.x;
    #pragma unroll
    for (int j = 0; j < 4; ++j) {
        const int c = (t >> 5) + 8 * j;
        sT[c][t & 31] = x[((size_t)b * CH + c0 + c) * N + n0 + (t & 31)];
    }
    __syncthreads();
    #pragma unroll
    for (int j = 0; j < 4; ++j) {
        const int n = (t >> 5) + 8 * j;
        xT[((size_t)b * N + n0 + n) * CH + c0 + (t & 31)] = f2bf(sT[t & 31][n]);
    }
}

// ---------------------------------------------------------------------------
// MFMA GEMM: out = xT * W^T + bias (1x1 conv).  64x64 tile. (proven in R2)
// ---------------------------------------------------------------------------
__global__ __launch_bounds__(256) void mfma_gemm(
    const short* __restrict__ xT, const float* __restrict__ W,
    const float* __restrict__ bias, short* __restrict__ out,
    int N, int O, int transp)
{
    __shared__ short sA[64][72];
    __shared__ short sB[64][72];
    const int b = blockIdx.z, i0 = blockIdx.x * 64, o0 = blockIdx.y * 64;
    const int t = threadIdx.x;
    const int lane = t & 63, w = t >> 6;
    const int quad = lane >> 4, l16 = lane & 15;
    const short* xb = xT + ((size_t)b * N + i0) * CH;

    f32x4 acc[4];
    const f32x4 zz = {0.f, 0.f, 0.f, 0.f};
    #pragma unroll
    for (int nt = 0; nt < 4; ++nt) acc[nt] = zz;

    for (int c0 = 0; c0 < CH; c0 += 64) {
        #pragma unroll
        for (int s = 0; s < 2; ++s) {
            const int id = t + s * 256, r = id >> 3, ch = id & 7;
            *(float4*)&sA[r][ch * 8] = *(const float4*)&xb[(size_t)r * CH + c0 + ch * 8];
        }
        #pragma unroll
        for (int s = 0; s < 4; ++s) {
            const int id = t + s * 256, r = id >> 4, ch = id & 15;
            const float4 wv = *(const float4*)&W[(size_t)(o0 + r) * CH + c0 + ch * 4];
            uint2 p;
            p.x = (unsigned short)f2bf(wv.x) | ((unsigned)(unsigned short)f2bf(wv.y) << 16);
            p.y = (unsigned short)f2bf(wv.z) | ((unsigned)(unsigned short)f2bf(wv.w) << 16);
            *(uint2*)&sB[r][ch * 4] = p;
        }
        __syncthreads();
        #pragma unroll
        for (int kk = 0; kk < 64; kk += 32) {
            const bf16x8 af = *(const bf16x8*)&sA[w * 16 + l16][kk + quad * 8];
            #pragma unroll
            for (int nt = 0; nt < 4; ++nt) {
                const bf16x8 bfr = *(const bf16x8*)&sB[nt * 16 + l16][kk + quad * 8];
                acc[nt] = __builtin_amdgcn_mfma_f32_16x16x32_bf16(af, bfr, acc[nt], 0, 0, 0);
            }
        }
        __syncthreads();
    }

    #pragma unroll
    for (int nt = 0; nt < 4; ++nt) {
        const int o = nt * 16 + l16;
        const float bb = bias[o0 + o];
        #pragma unroll
        for (int r = 0; r < 4; ++r) {
            const int i = w * 16 + quad * 4 + r;
            const short val = f2bf(acc[nt][r] + bb);
            if (transp) sA[o][i] = val; else sA[i][o] = val;
        }
    }
    __syncthreads();
    const int rr = t >> 2, part = t & 3;
    const int4 w0 = *(const int4*)&sA[rr][part * 16];
    const int4 w1 = *(const int4*)&sA[rr][part * 16 + 8];
    if (transp) {
        short* dst = out + ((size_t)b * O + o0 + rr) * N + i0 + part * 16;
        *(int4*)dst = w0; *(int4*)(dst + 8) = w1;
    } else {
        short* dst = out + ((size_t)b * N + i0 + rr) * O + o0 + part * 16;
        *(int4*)dst = w0; *(int4*)(dst + 8) = w1;
    }
}

// ---------------------------------------------------------------------------
// pmat: S = q.k^T (128i x 128j tile, K=64), U = exp(S-32) -> bf16, row sums
// via atomicAdd into lsum.  q,kT bf16 [b][n][64].  U bf16 rows of length n.
// ---------------------------------------------------------------------------
__global__ __launch_bounds__(256) void pmat(
    const short* __restrict__ q, const short* __restrict__ kT,
    short* __restrict__ U, float* __restrict__ lsum,
    int n, int bsel, int ibase)
{
    __shared__ char smem[36864 + 34816];
    short (*sQ)[72] = (short(*)[72])smem;           // 128 x 72
    short (*sK)[72] = (short(*)[72])(smem + 18432); // 128 x 72
    short (*sU)[136] = (short(*)[136])(smem + 36864);

    const int b = (bsel < 0) ? blockIdx.z : bsel;
    const int i0g = ibase + blockIdx.y * 128;
    const int j0 = blockIdx.x * 128;
    const size_t urow0 = (bsel < 0) ? ((size_t)b * n + i0g) : (size_t)(i0g - ibase);
    const int t = threadIdx.x;
    const int lane = t & 63;
    const int quad = lane >> 4, l16 = lane & 15;
    const int wrow = (t >> 6) & 1, wcol = t >> 7;

    // stage q-tile (chunks 0..1151) + k-tile (1152..2303); 9 x16B per thread
    {
        const short* Ab = q + ((size_t)b * n + i0g) * RED;
        const short* Bb = kT + ((size_t)b * n + j0) * RED;
        #pragma unroll
        for (int s = 0; s < 9; ++s) {
            const int c = s * 256 + t;
            const bool isA = c < 1152;
            const int tc = isA ? c : c - 1152;
            const int r = tc / 9, p = (tc % 9) & 7;
            const short* src = (isA ? Ab : Bb) + (size_t)r * RED + p * 8;
            gl16(src, smem + (size_t)c * 16);
        }
    }
    __syncthreads();

    f32x4 acc[4][4];
    const f32x4 zz = {0.f, 0.f, 0.f, 0.f};
    #pragma unroll
    for (int mi = 0; mi < 4; ++mi)
        #pragma unroll
        for (int ci = 0; ci < 4; ++ci) acc[mi][ci] = zz;

    #pragma unroll
    for (int kk = 0; kk < 64; kk += 32) {
        bf16x8 af[4], bfr[4];
        #pragma unroll
        for (int mi = 0; mi < 4; ++mi)
            af[mi] = *(const bf16x8*)&sQ[wrow * 64 + mi * 16 + l16][kk + quad * 8];
        #pragma unroll
        for (int ci = 0; ci < 4; ++ci)
            bfr[ci] = *(const bf16x8*)&sK[wcol * 64 + ci * 16 + l16][kk + quad * 8];
        #pragma unroll
        for (int mi = 0; mi < 4; ++mi)
            #pragma unroll
            for (int ci = 0; ci < 4; ++ci)
                acc[mi][ci] = __builtin_amdgcn_mfma_f32_16x16x32_bf16(af[mi], bfr[ci], acc[mi][ci], 0, 0, 0);
    }

    // exp, stash to sU, row-sum reduce, atomic add
    #pragma unroll
    for (int mi = 0; mi < 4; ++mi) {
        float rsum[4] = {0.f, 0.f, 0.f, 0.f};
        #pragma unroll
        for (int ci = 0; ci < 4; ++ci) {
            #pragma unroll
            for (int r = 0; r < 4; ++r) {
                const float e = __expf(acc[mi][ci][r] - 32.0f);
                sU[wrow * 64 + mi * 16 + quad * 4 + r][wcol * 64 + ci * 16 + l16] = f2bf(e);
                rsum[r] += e;
            }
        }
        #pragma unroll
        for (int r = 0; r < 4; ++r) {
            float v = rsum[r];
            #pragma unroll
            for (int off = 1; off < 16; off <<= 1) v += __shfl_xor(v, off);
            if (l16 == 0)
                atomicAdd(&lsum[(size_t)b * n + i0g + wrow * 64 + mi * 16 + quad * 4 + r], v);
        }
    }
    __syncthreads();

    // coalesced U store
    #pragma unroll
    for (int u = 0; u < 8; ++u) {
        const int id = u * 256 + t, row = id >> 4, part = id & 15;
        const int4 val = *(const int4*)&sU[row][part * 8];
        *(int4*)&U[(urow0 + row) * n + j0 + part * 8] = val;
    }
}

// ---------------------------------------------------------------------------
// pv_gemm: O[i][c] = sum_j U[i][j] * V[c][j]; y = g*(O/l) + x.
// 128i x 128c tile, BK=64, global_load_lds staging (stride-72 padded tiles),
// 4 waves (2x2), 32 MFMA per barrier pair.
// ---------------------------------------------------------------------------
__global__ __launch_bounds__(256) void pv_gemm(
    const short* __restrict__ U,   // bf16 rows of length n
    const short* __restrict__ V,   // bf16 [b][CH][n]
    const float* __restrict__ lsum,
    const float* __restrict__ x, const float* __restrict__ gamma,
    float* __restrict__ y,
    int n, int bsel, int ibase)
{
    __shared__ char smem[36864];
    short (*sA)[72] = (short(*)[72])smem;
    short (*sB)[72] = (short(*)[72])(smem + 18432);

    const int b = (bsel < 0) ? blockIdx.z : bsel;
    const int i0g = ibase + blockIdx.x * 128;
    const int c0 = blockIdx.y * 128;
    const size_t urow0 = (bsel < 0) ? ((size_t)b * n + i0g) : (size_t)(i0g - ibase);
    const int t = threadIdx.x;
    const int lane = t & 63;
    const int quad = lane >> 4, l16 = lane & 15;
    const int wrow = (t >> 6) & 1, wcol = t >> 7;

    f32x4 acc[4][4];
    const f32x4 zz = {0.f, 0.f, 0.f, 0.f};
    #pragma unroll
    for (int mi = 0; mi < 4; ++mi)
        #pragma unroll
        for (int ci = 0; ci < 4; ++ci) acc[mi][ci] = zz;

    const short* Ab = U + urow0 * n;
    const short* Bb = V + ((size_t)b * CH + c0) * n;

    for (int j0 = 0; j0 < n; j0 += 64) {
        #pragma unroll
        for (int s = 0; s < 9; ++s) {
            const int c = s * 256 + t;
            const bool isA = c < 1152;
            const int tc = isA ? c : c - 1152;
            const int r = tc / 9, p = (tc % 9) & 7;
            const short* src = (isA ? Ab : Bb) + (size_t)r * n + j0 + p * 8;
            gl16(src, smem + (size_t)c * 16);
        }
        __syncthreads();
        #pragma unroll
        for (int kk = 0; kk < 64; kk += 32) {
            bf16x8 af[4], bfr[4];
            #pragma unroll
            for (int mi = 0; mi < 4; ++mi)
                af[mi] = *(const bf16x8*)&sA[wrow * 64 + mi * 16 + l16][kk + quad * 8];
            #pragma unroll
            for (int ci = 0; ci < 4; ++ci)
                bfr[ci] = *(const bf16x8*)&sB[wcol * 64 + ci * 16 + l16][kk + quad * 8];
            #pragma unroll
            for (int mi = 0; mi < 4; ++mi)
                #pragma unroll
                for (int ci = 0; ci < 4; ++ci)
                    acc[mi][ci] = __builtin_amdgcn_mfma_f32_16x16x32_bf16(af[mi], bfr[ci], acc[mi][ci], 0, 0, 0);
        }
        __syncthreads();
    }

    // 1/l per output row
    float ilr[4][4];
    #pragma unroll
    for (int mi = 0; mi < 4; ++mi)
        #pragma unroll
        for (int r = 0; r < 4; ++r)
            ilr[mi][r] = 1.0f / lsum[(size_t)b * n + i0g + wrow * 64 + mi * 16 + quad * 4 + r];

    const float g = gamma[0];
    float (*sep)[133] = (float(*)[133])smem;   // 32 x 133 f32 = 17 KB

    #pragma unroll
    for (int cc = 0; cc < 4; ++cc) {
        __syncthreads();
        if ((cc >> 1) == wcol) {
            #pragma unroll
            for (int cs = 0; cs < 2; ++cs) {
                const int ci = (cc & 1) * 2 + cs;
                #pragma unroll
                for (int mi = 0; mi < 4; ++mi)
                    #pragma unroll
                    for (int r = 0; r < 4; ++r)
                        sep[cs * 16 + l16][wrow * 64 + mi * 16 + quad * 4 + r] =
                            acc[mi][ci][r] * ilr[mi][r];
            }
        }
        __syncthreads();
        const int crow = t >> 3, seg = t & 7;
        const size_t gb = ((size_t)b * CH + c0 + cc * 32 + crow) * n + i0g + seg * 16;
        #pragma unroll
        for (int u = 0; u < 4; ++u) {
            const float4 xv = *(const float4*)&x[gb + u * 4];
            float4 ov;
            ov.x = g * sep[crow][seg * 16 + u * 4 + 0] + xv.x;
            ov.y = g * sep[crow][seg * 16 + u * 4 + 1] + xv.y;
            ov.z = g * sep[crow][seg * 16 + u * 4 + 2] + xv.z;
            ov.w = g * sep[crow][seg * 16 + u * 4 + 3] + xv.w;
            *(float4*)&y[gb + u * 4] = ov;
        }
    }
}

// ---------------------------------------------------------------------------
extern "C" void kernel_launch(void* const* d_in, const int* in_sizes, int n_in,
                              void* d_out, int out_size, void* d_ws, size_t ws_size,
                              hipStream_t stream) {
    const float* x     = (const float*)d_in[0];
    const float* Wq    = (const float*)d_in[1];
    const float* bq    = (const float*)d_in[2];
    const float* Wk    = (const float*)d_in[3];
    const float* bk    = (const float*)d_in[4];
    const float* Wv    = (const float*)d_in[5];
    const float* bv    = (const float*)d_in[6];
    const float* gamma = (const float*)d_in[7];
    float* y = (float*)d_out;

    const int N = 64 * 64;
    const int B = in_sizes[0] / (CH * N);   // = 4

    // ws layout: xT | qB | kB | v2 | lB | U
    char* ws = (char*)d_ws;
    short* xT = (short*)ws;   ws += (size_t)B * N * CH * 2;
    short* qB = (short*)ws;   ws += (size_t)B * N * RED * 2;
    short* kB = (short*)ws;   ws += (size_t)B * N * RED * 2;
    short* v2 = (short*)ws;   ws += (size_t)B * CH * N * 2;
    float* lB = (float*)ws;   ws += (size_t)B * N * 4;
    short* Ubuf = (short*)ws;
    const size_t head = (size_t)(ws - (char*)d_ws);
    const size_t avail = (ws_size > head) ? (ws_size - head) : 0;

    hipMemsetAsync(lB, 0, (size_t)B * N * 4, stream);

    cast_transpose<<<dim3(N / 32, CH / 32, B), 256, 0, stream>>>(x, xT, N);
    mfma_gemm<<<dim3(N / 64, RED / 64, B), 256, 0, stream>>>(xT, Wq, bq, qB, N, RED, 0);
    mfma_gemm<<<dim3(N / 64, RED / 64, B), 256, 0, stream>>>(xT, Wk, bk, kB, N, RED, 0);
    mfma_gemm<<<dim3(N / 64, CH / 64, B), 256, 0, stream>>>(xT, Wv, bv, v2, N, CH, 1);

    const size_t fullU = (size_t)B * N * N * 2;
    if (avail >= fullU) {
        // single-shot: U holds all batches
        pmat<<<dim3(N / 128, N / 128, B), 256, 0, stream>>>(qB, kB, Ubuf, lB, N, -1, 0);
        pv_gemm<<<dim3(N / 128, CH / 128, B), 256, 0, stream>>>(Ubuf, v2, lB, x, gamma, y, N, -1, 0);
    } else {
        // chunked: U reused per (batch, row-chunk); rows multiple of 128
        size_t rows = avail / ((size_t)N * 2);
        rows = (rows / 128) * 128;
        if (rows > (size_t)N) rows = N;
        if (rows < 128) rows = 128;   // last-resort; requires ~41 MB ws
        for (int b = 0; b < B; ++b) {
            for (int ib = 0; ib < N; ib += (int)rows) {
                const int rc = ((N - ib) < (int)rows) ? (N - ib) : (int)rows;
                pmat<<<dim3(N / 128, rc / 128, 1), 256, 0, stream>>>(qB, kB, Ubuf, lB, N, b, ib);
                pv_gemm<<<dim3(rc / 128, CH / 128, 1), 256, 0, stream>>>(Ubuf, v2, lB, x, gamma, y, N, b, ib);
            }
        }
    }
}

// Round 4
// 318.982 us; speedup vs baseline: 5.8490x; 1.0541x over previous
//
#include <hip/hip_runtime.h>
#include <math.h>

#define CH 512
#define RED 64

typedef __attribute__((ext_vector_type(8))) short bf16x8;
typedef __attribute__((ext_vector_type(4))) float f32x4;

typedef const __attribute__((address_space(1))) void* gas_t;
typedef __attribute__((address_space(3))) void* las_t;

static __device__ __forceinline__ short f2bf(float f) {
    union { float f; unsigned u; } v; v.f = f;
    unsigned r = (v.u + 0x7FFF + ((v.u >> 16) & 1)) >> 16;
    return (short)r;
}

static __device__ __forceinline__ void gl16(const void* g, void* l) {
    __builtin_amdgcn_global_load_lds((gas_t)g, (las_t)l, 16, 0, 0);
}

// ---------------------------------------------------------------------------
// x f32 [b][c][n] -> xT bf16 [b][n][c].  32x32 tiles.
// ---------------------------------------------------------------------------
__global__ __launch_bounds__(256) void cast_transpose(
    const float* __restrict__ x, short* __restrict__ xT, int N)
{
    __shared__ float sT[32][33];
    const int b = blockIdx.z, n0 = blockIdx.x * 32, c0 = blockIdx.y * 32;
    const int t = threadIdx.x;
    #pragma unroll
    for (int j = 0; j < 4; ++j) {
        const int c = (t >> 5) + 8 * j;
        sT[c][t & 31] = x[((size_t)b * CH + c0 + c) * N + n0 + (t & 31)];
    }
    __syncthreads();
    #pragma unroll
    for (int j = 0; j < 4; ++j) {
        const int n = (t >> 5) + 8 * j;
        xT[((size_t)b * N + n0 + n) * CH + c0 + (t & 31)] = f2bf(sT[t & 31][n]);
    }
}

// ---------------------------------------------------------------------------
// MFMA GEMM (proven R2/R3): out = xT * W^T + bias.  64x64 tile.
// transp=1 -> out [b][O][N], else [b][N][O].
// ---------------------------------------------------------------------------
__global__ __launch_bounds__(256) void mfma_gemm(
    const short* __restrict__ xT, const float* __restrict__ W,
    const float* __restrict__ bias, short* __restrict__ out,
    int N, int O, int transp)
{
    __shared__ short sA[64][72];
    __shared__ short sB[64][72];
    const int b = blockIdx.z, i0 = blockIdx.x * 64, o0 = blockIdx.y * 64;
    const int t = threadIdx.x;
    const int lane = t & 63, w = t >> 6;
    const int quad = lane >> 4, l16 = lane & 15;
    const short* xb = xT + ((size_t)b * N + i0) * CH;

    f32x4 acc[4];
    const f32x4 zz = {0.f, 0.f, 0.f, 0.f};
    #pragma unroll
    for (int nt = 0; nt < 4; ++nt) acc[nt] = zz;

    for (int c0 = 0; c0 < CH; c0 += 64) {
        #pragma unroll
        for (int s = 0; s < 2; ++s) {
            const int id = t + s * 256, r = id >> 3, ch = id & 7;
            *(float4*)&sA[r][ch * 8] = *(const float4*)&xb[(size_t)r * CH + c0 + ch * 8];
        }
        #pragma unroll
        for (int s = 0; s < 4; ++s) {
            const int id = t + s * 256, r = id >> 4, ch = id & 15;
            const float4 wv = *(const float4*)&W[(size_t)(o0 + r) * CH + c0 + ch * 4];
            uint2 p;
            p.x = (unsigned short)f2bf(wv.x) | ((unsigned)(unsigned short)f2bf(wv.y) << 16);
            p.y = (unsigned short)f2bf(wv.z) | ((unsigned)(unsigned short)f2bf(wv.w) << 16);
            *(uint2*)&sB[r][ch * 4] = p;
        }
        __syncthreads();
        #pragma unroll
        for (int kk = 0; kk < 64; kk += 32) {
            const bf16x8 af = *(const bf16x8*)&sA[w * 16 + l16][kk + quad * 8];
            #pragma unroll
            for (int nt = 0; nt < 4; ++nt) {
                const bf16x8 bfr = *(const bf16x8*)&sB[nt * 16 + l16][kk + quad * 8];
                acc[nt] = __builtin_amdgcn_mfma_f32_16x16x32_bf16(af, bfr, acc[nt], 0, 0, 0);
            }
        }
        __syncthreads();
    }

    #pragma unroll
    for (int nt = 0; nt < 4; ++nt) {
        const int o = nt * 16 + l16;
        const float bb = bias[o0 + o];
        #pragma unroll
        for (int r = 0; r < 4; ++r) {
            const int i = w * 16 + quad * 4 + r;
            const short val = f2bf(acc[nt][r] + bb);
            if (transp) sA[o][i] = val; else sA[i][o] = val;
        }
    }
    __syncthreads();
    const int rr = t >> 2, part = t & 3;
    const int4 w0 = *(const int4*)&sA[rr][part * 16];
    const int4 w1 = *(const int4*)&sA[rr][part * 16 + 8];
    if (transp) {
        short* dst = out + ((size_t)b * O + o0 + rr) * N + i0 + part * 16;
        *(int4*)dst = w0; *(int4*)(dst + 8) = w1;
    } else {
        short* dst = out + ((size_t)b * N + i0 + rr) * O + o0 + part * 16;
        *(int4*)dst = w0; *(int4*)(dst + 8) = w1;
    }
}

// ---------------------------------------------------------------------------
// q AND k projection in one launch: blockIdx.y selects (W,b,out). O=RED=64.
// ---------------------------------------------------------------------------
__global__ __launch_bounds__(256) void qk_gemm(
    const short* __restrict__ xT,
    const float* __restrict__ Wq, const float* __restrict__ bq, short* __restrict__ outq,
    const float* __restrict__ Wk, const float* __restrict__ bk, short* __restrict__ outk,
    int N)
{
    __shared__ short sA[64][72];
    __shared__ short sB[64][72];
    const int b = blockIdx.z, i0 = blockIdx.x * 64;
    const int sel = blockIdx.y;
    const float* W = sel ? Wk : Wq;
    const float* bias = sel ? bk : bq;
    short* out = sel ? outk : outq;
    const int t = threadIdx.x;
    const int lane = t & 63, w = t >> 6;
    const int quad = lane >> 4, l16 = lane & 15;
    const short* xb = xT + ((size_t)b * N + i0) * CH;

    f32x4 acc[4];
    const f32x4 zz = {0.f, 0.f, 0.f, 0.f};
    #pragma unroll
    for (int nt = 0; nt < 4; ++nt) acc[nt] = zz;

    for (int c0 = 0; c0 < CH; c0 += 64) {
        #pragma unroll
        for (int s = 0; s < 2; ++s) {
            const int id = t + s * 256, r = id >> 3, ch = id & 7;
            *(float4*)&sA[r][ch * 8] = *(const float4*)&xb[(size_t)r * CH + c0 + ch * 8];
        }
        #pragma unroll
        for (int s = 0; s < 4; ++s) {
            const int id = t + s * 256, r = id >> 4, ch = id & 15;
            const float4 wv = *(const float4*)&W[(size_t)r * CH + c0 + ch * 4];
            uint2 p;
            p.x = (unsigned short)f2bf(wv.x) | ((unsigned)(unsigned short)f2bf(wv.y) << 16);
            p.y = (unsigned short)f2bf(wv.z) | ((unsigned)(unsigned short)f2bf(wv.w) << 16);
            *(uint2*)&sB[r][ch * 4] = p;
        }
        __syncthreads();
        #pragma unroll
        for (int kk = 0; kk < 64; kk += 32) {
            const bf16x8 af = *(const bf16x8*)&sA[w * 16 + l16][kk + quad * 8];
            #pragma unroll
            for (int nt = 0; nt < 4; ++nt) {
                const bf16x8 bfr = *(const bf16x8*)&sB[nt * 16 + l16][kk + quad * 8];
                acc[nt] = __builtin_amdgcn_mfma_f32_16x16x32_bf16(af, bfr, acc[nt], 0, 0, 0);
            }
        }
        __syncthreads();
    }

    #pragma unroll
    for (int nt = 0; nt < 4; ++nt) {
        const float bb = bias[nt * 16 + l16];
        #pragma unroll
        for (int r = 0; r < 4; ++r)
            sA[w * 16 + quad * 4 + r][nt * 16 + l16] = f2bf(acc[nt][r] + bb);
    }
    __syncthreads();
    const int rr = t >> 2, part = t & 3;
    const int4 w0 = *(const int4*)&sA[rr][part * 16];
    const int4 w1 = *(const int4*)&sA[rr][part * 16 + 8];
    short* dst = out + ((size_t)b * N + i0 + rr) * RED + part * 16;
    *(int4*)dst = w0; *(int4*)(dst + 8) = w1;
}

// ---------------------------------------------------------------------------
// Fused attention: per block 64 queries x all 512 channels, j in chunks of 64.
// S = qk^T via MFMA, P = exp(S-32) (bf16, LDS), O += P V^T via MFMA,
// l accumulated in-register; epilogue y = g*(O/l) + x.
// 1024 threads (16 waves): wave w -> S-tile (mi=w&3, mj=w>>2);
// PV: i-strip mi*16, c-range mj*128 (8 c-tiles).  99 KB LDS, 3 barriers/chunk.
// ---------------------------------------------------------------------------
__global__ __launch_bounds__(1024, 4) void attn_fused(
    const short* __restrict__ q,    // [b][n][64] bf16
    const short* __restrict__ kT,   // [b][n][64] bf16
    const short* __restrict__ v2,   // [b][512][n] bf16
    const float* __restrict__ x,    // [b][512][n] f32
    const float* __restrict__ gamma,
    float* __restrict__ y, int n)
{
    __shared__ char smem[101376];
    short (*sQ)[72] = (short(*)[72])smem;             // 64 x 72
    short (*sK)[72] = (short(*)[72])(smem + 9216);    // 64 x 72
    short (*sP)[72] = (short(*)[72])(smem + 18432);   // 64 x 72
    short (*sV)[72] = (short(*)[72])(smem + 27648);   // 512 x 72

    const int b = blockIdx.y, i0 = blockIdx.x * 64;
    const int t = threadIdx.x;
    const int lane = t & 63, w = t >> 6;
    const int quad = lane >> 4, l16 = lane & 15;
    const int mi = w & 3, mj = w >> 2;

    // stage Q once (576 x 16B chunks; stride 72 shorts = 9 chunks/row)
    {
        const short* Qb = q + ((size_t)b * n + i0) * RED;
        if (t < 576) {
            const int r = t / 9, p = (t % 9) & 7;
            gl16(Qb + (size_t)r * RED + p * 8, smem + t * 16);
        }
    }

    f32x4 acc[8];
    const f32x4 zz = {0.f, 0.f, 0.f, 0.f};
    #pragma unroll
    for (int ct = 0; ct < 8; ++ct) acc[ct] = zz;
    float lacc[4] = {0.f, 0.f, 0.f, 0.f};

    for (int j0 = 0; j0 < n; j0 += 64) {
        __syncthreads();   // prior chunk's reads of sK/sV/sP complete (also drains Q on iter 0)
        {
            const short* Kb = kT + ((size_t)b * n + j0) * RED;
            const short* Vb = v2 + (size_t)b * CH * n + j0;
            if (t < 576) {
                const int r = t / 9, p = (t % 9) & 7;
                gl16(Kb + (size_t)r * RED + p * 8, smem + 9216 + t * 16);
            }
            #pragma unroll
            for (int s = 0; s < 4; ++s) {
                const int c = s * 1024 + t;
                const int r = c / 9, p = (c % 9) & 7;
                gl16(Vb + (size_t)r * n + p * 8, smem + 27648 + (size_t)c * 16);
            }
            if (t < 512) {
                const int c = 4096 + t;
                const int r = c / 9, p = (c % 9) & 7;
                gl16(Vb + (size_t)r * n + p * 8, smem + 27648 + (size_t)c * 16);
            }
        }
        __syncthreads();   // drain staging

        // S tile (mi, mj): 16x16, k=64
        f32x4 S = zz;
        #pragma unroll
        for (int kk = 0; kk < 64; kk += 32) {
            const bf16x8 af = *(const bf16x8*)&sQ[mi * 16 + l16][kk + quad * 8];
            const bf16x8 bfr = *(const bf16x8*)&sK[mj * 16 + l16][kk + quad * 8];
            S = __builtin_amdgcn_mfma_f32_16x16x32_bf16(af, bfr, S, 0, 0, 0);
        }
        // P = exp(S - 32), accumulate row-partials, stash bf16
        #pragma unroll
        for (int r = 0; r < 4; ++r) {
            const float e = __expf(S[r] - 32.0f);
            lacc[r] += e;
            sP[mi * 16 + quad * 4 + r][mj * 16 + l16] = f2bf(e);
        }
        __syncthreads();   // P visible

        // PV: wave w -> rows mi*16..+15, channels mj*128..+127 (8 tiles)
        #pragma unroll
        for (int kk = 0; kk < 64; kk += 32) {
            const bf16x8 af = *(const bf16x8*)&sP[mi * 16 + l16][kk + quad * 8];
            #pragma unroll
            for (int ct = 0; ct < 8; ++ct) {
                const bf16x8 bfr = *(const bf16x8*)&sV[mj * 128 + ct * 16 + l16][kk + quad * 8];
                acc[ct] = __builtin_amdgcn_mfma_f32_16x16x32_bf16(af, bfr, acc[ct], 0, 0, 0);
            }
        }
    }

    // l reduction: sum over 16 lanes, then over 4 mj-waves via LDS
    float* sLp = (float*)(smem + 9216);   // [mj][64] = 1 KB, aliases sK
    __syncthreads();
    #pragma unroll
    for (int r = 0; r < 4; ++r) {
        float v = lacc[r];
        #pragma unroll
        for (int off = 1; off < 16; off <<= 1) v += __shfl_xor(v, off);
        if (l16 == 0) sLp[mj * 64 + mi * 16 + quad * 4 + r] = v;
    }
    __syncthreads();
    float il[4];
    #pragma unroll
    for (int r = 0; r < 4; ++r) {
        const int row = mi * 16 + quad * 4 + r;
        il[r] = 1.0f / (sLp[row] + sLp[64 + row] + sLp[128 + row] + sLp[192 + row]);
    }

    // Epilogue: transpose 256-channel halves through LDS (aliases sV), y = g*(O/l) + x
    const float g = gamma[0];
    float (*sT)[66] = (float(*)[66])(smem + 27648);   // 256 x 66 f32 = 67.6 KB
    #pragma unroll
    for (int half = 0; half < 2; ++half) {
        __syncthreads();
        if ((mj >> 1) == half) {
            const int cb = (mj & 1) * 128;
            #pragma unroll
            for (int ct = 0; ct < 8; ++ct)
                #pragma unroll
                for (int r = 0; r < 4; ++r)
                    sT[cb + ct * 16 + l16][mi * 16 + quad * 4 + r] = acc[ct][r] * il[r];
        }
        __syncthreads();
        const int cr = t >> 2, seg = t & 3;
        const size_t gb = ((size_t)b * CH + half * 256 + cr) * n + i0 + seg * 16;
        #pragma unroll
        for (int u = 0; u < 4; ++u) {
            const float4 xv = *(const float4*)&x[gb + u * 4];
            float4 ov;
            ov.x = g * sT[cr][seg * 16 + u * 4 + 0] + xv.x;
            ov.y = g * sT[cr][seg * 16 + u * 4 + 1] + xv.y;
            ov.z = g * sT[cr][seg * 16 + u * 4 + 2] + xv.z;
            ov.w = g * sT[cr][seg * 16 + u * 4 + 3] + xv.w;
            *(float4*)&y[gb + u * 4] = ov;
        }
    }
}

// ---------------------------------------------------------------------------
extern "C" void kernel_launch(void* const* d_in, const int* in_sizes, int n_in,
                              void* d_out, int out_size, void* d_ws, size_t ws_size,
                              hipStream_t stream) {
    const float* x     = (const float*)d_in[0];
    const float* Wq    = (const float*)d_in[1];
    const float* bq    = (const float*)d_in[2];
    const float* Wk    = (const float*)d_in[3];
    const float* bk    = (const float*)d_in[4];
    const float* Wv    = (const float*)d_in[5];
    const float* bv    = (const float*)d_in[6];
    const float* gamma = (const float*)d_in[7];
    float* y = (float*)d_out;

    const int N = 64 * 64;
    const int B = in_sizes[0] / (CH * N);   // = 4

    // ws: xT 16.8M | q 2.1M | k 2.1M | v2 16.8M  ~= 37.8 MB
    char* ws = (char*)d_ws;
    short* xT = (short*)ws;   ws += (size_t)B * N * CH * 2;
    short* qB = (short*)ws;   ws += (size_t)B * N * RED * 2;
    short* kB = (short*)ws;   ws += (size_t)B * N * RED * 2;
    short* v2 = (short*)ws;

    cast_transpose<<<dim3(N / 32, CH / 32, B), 256, 0, stream>>>(x, xT, N);
    qk_gemm<<<dim3(N / 64, 2, B), 256, 0, stream>>>(xT, Wq, bq, qB, Wk, bk, kB, N);
    mfma_gemm<<<dim3(N / 64, CH / 64, B), 256, 0, stream>>>(xT, Wv, bv, v2, N, CH, 1);

    attn_fused<<<dim3(N / 64, B), 1024, 0, stream>>>(qB, kB, v2, x, gamma, y, N);
}

// Round 5
// 258.882 us; speedup vs baseline: 7.2068x; 1.2322x over previous
//
#include <hip/hip_runtime.h>
#include <math.h>

#define CH 512
#define RED 64

typedef __attribute__((ext_vector_type(8))) short bf16x8;
typedef __attribute__((ext_vector_type(4))) float f32x4;

typedef const __attribute__((address_space(1))) void* gas_t;
typedef __attribute__((address_space(3))) void* las_t;

static __device__ __forceinline__ short f2bf(float f) {
    union { float f; unsigned u; } v; v.f = f;
    unsigned r = (v.u + 0x7FFF + ((v.u >> 16) & 1)) >> 16;
    return (short)r;
}

static __device__ __forceinline__ void gl16(const void* g, void* l) {
    __builtin_amdgcn_global_load_lds((gas_t)g, (las_t)l, 16, 0, 0);
}

// ---------------------------------------------------------------------------
// prep_w: Wq|Wk|Wv f32 -> Wcat bf16 [640][512]. rows: 0-63 q, 64-127 k, 128-639 v.
// ---------------------------------------------------------------------------
__global__ __launch_bounds__(256) void prep_w(
    const float* __restrict__ Wq, const float* __restrict__ Wk,
    const float* __restrict__ Wv, short* __restrict__ Wcat)
{
    const int r = blockIdx.x, t = threadIdx.x;
    const float* src = (r < 64) ? (Wq + (size_t)r * CH)
                     : (r < 128) ? (Wk + (size_t)(r - 64) * CH)
                                 : (Wv + (size_t)(r - 128) * CH);
    const float a = src[2 * t], b = src[2 * t + 1];
    unsigned p = (unsigned short)f2bf(a) | ((unsigned)(unsigned short)f2bf(b) << 16);
    *(unsigned*)&Wcat[(size_t)r * CH + 2 * t] = p;
}

// ---------------------------------------------------------------------------
// qkv_fused: per block, 64-i tile; sel=blockIdx.y:
//   sel=0: q[b][i][64] + v2 channels [0,256);  sel=1: k[b][i][64] + v2 [256,512).
// x f32 [b][c][n] read once, transposed to bf16 A-tiles via LDS writes.
// Weights staged bf16 via global_load_lds.  256 thr, 55 KB LDS -> 2 blocks/CU.
// ---------------------------------------------------------------------------
__global__ __launch_bounds__(256) void qkv_fused(
    const float* __restrict__ x, const short* __restrict__ Wcat,
    const float* __restrict__ bq, const float* __restrict__ bk,
    const float* __restrict__ bv,
    short* __restrict__ qB, short* __restrict__ kB, short* __restrict__ v2,
    int n)
{
    __shared__ char smem[55296];
    short (*sA)[72]  = (short(*)[72])smem;            // 64 x 72  x-tile (transposed)
    short (*sW)[72]  = (short(*)[72])(smem + 9216);   // 64 x 72  q-or-k weights
    short (*sWv)[72] = (short(*)[72])(smem + 18432);  // 256 x 72 v-weight half

    const int b = blockIdx.z, i0 = blockIdx.x * 64, sel = blockIdx.y;
    const int t = threadIdx.x;
    const int lane = t & 63, w = t >> 6;
    const int quad = lane >> 4, l16 = lane & 15;

    f32x4 acc_qk[4], acc_v[16];
    const f32x4 zz = {0.f, 0.f, 0.f, 0.f};
    #pragma unroll
    for (int nt = 0; nt < 4; ++nt) acc_qk[nt] = zz;
    #pragma unroll
    for (int nt = 0; nt < 16; ++nt) acc_v[nt] = zz;

    const short* Wqk = Wcat + (size_t)(sel * 64) * CH;
    const short* Wvh = Wcat + (size_t)(128 + sel * 256) * CH;

    for (int c0 = 0; c0 < CH; c0 += 64) {
        // x tile: load f32 [64c x 64i] coalesced along i, transpose-store bf16
        {
            const int i4 = (t & 15) * 4, cr = t >> 4;
            #pragma unroll
            for (int s = 0; s < 4; ++s) {
                const int c = cr + 16 * s;
                const float4 xv = *(const float4*)&x[((size_t)b * CH + c0 + c) * n + i0 + i4];
                sA[i4 + 0][c] = f2bf(xv.x);
                sA[i4 + 1][c] = f2bf(xv.y);
                sA[i4 + 2][c] = f2bf(xv.z);
                sA[i4 + 3][c] = f2bf(xv.w);
            }
        }
        // qk weights: 576 chunks
        #pragma unroll
        for (int s = 0; s < 2; ++s) {
            const int c = s * 256 + t, r = c / 9, p = (c % 9) & 7;
            gl16(Wqk + (size_t)r * CH + c0 + p * 8, smem + 9216 + (size_t)c * 16);
        }
        if (t < 64) {
            const int c = 512 + t, r = c / 9, p = (c % 9) & 7;
            gl16(Wqk + (size_t)r * CH + c0 + p * 8, smem + 9216 + (size_t)c * 16);
        }
        // v weights: 2304 chunks
        #pragma unroll
        for (int s = 0; s < 9; ++s) {
            const int c = s * 256 + t, r = c / 9, p = (c % 9) & 7;
            gl16(Wvh + (size_t)r * CH + c0 + p * 8, smem + 18432 + (size_t)c * 16);
        }
        __syncthreads();
        #pragma unroll
        for (int kk = 0; kk < 64; kk += 32) {
            const bf16x8 af = *(const bf16x8*)&sA[w * 16 + l16][kk + quad * 8];
            #pragma unroll
            for (int nt = 0; nt < 4; ++nt) {
                const bf16x8 bfr = *(const bf16x8*)&sW[nt * 16 + l16][kk + quad * 8];
                acc_qk[nt] = __builtin_amdgcn_mfma_f32_16x16x32_bf16(af, bfr, acc_qk[nt], 0, 0, 0);
            }
            #pragma unroll
            for (int nt = 0; nt < 16; ++nt) {
                const bf16x8 bfr = *(const bf16x8*)&sWv[nt * 16 + l16][kk + quad * 8];
                acc_v[nt] = __builtin_amdgcn_mfma_f32_16x16x32_bf16(af, bfr, acc_v[nt], 0, 0, 0);
            }
        }
        __syncthreads();
    }

    // Epilogue: qk -> [b][i][64] via sA bounce; v -> [b][c][n] via sWv bounce.
    const float* bqk = sel ? bk : bq;
    #pragma unroll
    for (int nt = 0; nt < 4; ++nt) {
        const float bb = bqk[nt * 16 + l16];
        #pragma unroll
        for (int r = 0; r < 4; ++r)
            sA[w * 16 + quad * 4 + r][nt * 16 + l16] = f2bf(acc_qk[nt][r] + bb);
    }
    short (*sV2)[72] = sWv;
    #pragma unroll
    for (int nt = 0; nt < 16; ++nt) {
        const float bb = bv[sel * 256 + nt * 16 + l16];
        #pragma unroll
        for (int r = 0; r < 4; ++r)
            sV2[nt * 16 + l16][w * 16 + quad * 4 + r] = f2bf(acc_v[nt][r] + bb);
    }
    __syncthreads();
    {
        short* outqk = (sel ? kB : qB) + ((size_t)b * n + i0) * RED;
        const int rr = t >> 2, part = t & 3;
        const int4 w0 = *(const int4*)&sA[rr][part * 16];
        const int4 w1 = *(const int4*)&sA[rr][part * 16 + 8];
        short* dst = outqk + (size_t)rr * RED + part * 16;
        *(int4*)dst = w0; *(int4*)(dst + 8) = w1;
    }
    #pragma unroll
    for (int u = 0; u < 8; ++u) {
        const int id = u * 256 + t, row = id >> 3, part = id & 7;
        *(int4*)&v2[((size_t)b * CH + sel * 256 + row) * n + i0 + part * 8] =
            *(const int4*)&sV2[row][part * 8];
    }
}

// ---------------------------------------------------------------------------
// attn_fused512: 64 queries x 256 channels (half=blockIdx.y), 512 thr (8 waves),
// 63 KB LDS -> 2 blocks/CU.  j chunks of 64: S=qk^T, P=exp(S-32) bf16,
// O += P V^T; l in-register; epilogue y = g*(O/l) + x.
// wave w: mi=w&3 (16-row i-strip), jg=w>>2 (32-j / 128-channel group).
// ---------------------------------------------------------------------------
__global__ __launch_bounds__(512) void attn_fused512(
    const short* __restrict__ q,    // [b][n][64] bf16
    const short* __restrict__ kT,   // [b][n][64] bf16
    const short* __restrict__ v2,   // [b][512][n] bf16
    const float* __restrict__ x,    // [b][512][n] f32
    const float* __restrict__ gamma,
    float* __restrict__ y, int n)
{
    __shared__ char smem[64512];
    short (*sQ)[72] = (short(*)[72])smem;             // 64 x 72
    short (*sK)[72] = (short(*)[72])(smem + 9216);    // 64 x 72
    short (*sP)[72] = (short(*)[72])(smem + 18432);   // 64 x 72
    short (*sV)[72] = (short(*)[72])(smem + 27648);   // 256 x 72

    const int b = blockIdx.z, i0 = blockIdx.x * 64, half = blockIdx.y;
    const int t = threadIdx.x;
    const int lane = t & 63, w = t >> 6;
    const int quad = lane >> 4, l16 = lane & 15;
    const int mi = w & 3, jg = w >> 2;

    // stage Q once: 576 x 16B chunks
    {
        const short* Qb = q + ((size_t)b * n + i0) * RED;
        { const int r = t / 9, p = (t % 9) & 7;
          gl16(Qb + (size_t)r * RED + p * 8, smem + (size_t)t * 16); }
        if (t < 64) {
            const int c = 512 + t, r = c / 9, p = (c % 9) & 7;
            gl16(Qb + (size_t)r * RED + p * 8, smem + (size_t)c * 16);
        }
    }

    f32x4 acc[8];
    const f32x4 zz = {0.f, 0.f, 0.f, 0.f};
    #pragma unroll
    for (int ct = 0; ct < 8; ++ct) acc[ct] = zz;
    float lacc[4] = {0.f, 0.f, 0.f, 0.f};

    const short* Kb0 = kT + (size_t)b * n * RED;
    const short* Vb0 = v2 + ((size_t)b * CH + half * 256) * n;

    for (int j0 = 0; j0 < n; j0 += 64) {
        __syncthreads();   // prior chunk's reads of sK/sV/sP done (drains Q gl16 on iter 0)
        {
            const short* Kb = Kb0 + (size_t)j0 * RED;
            #pragma unroll
            for (int s = 0; s < 5; ++s) {
                const int c = s * 512 + t;
                if (c < 576) {
                    const int r = c / 9, p = (c % 9) & 7;
                    gl16(Kb + (size_t)r * RED + p * 8, smem + 9216 + (size_t)c * 16);
                } else {
                    const int vc = c - 576, r = vc / 9, p = (vc % 9) & 7;
                    gl16(Vb0 + (size_t)r * n + j0 + p * 8, smem + 27648 + (size_t)vc * 16);
                }
            }
            if (t < 320) {
                const int vc = 1984 + t, r = vc / 9, p = (vc % 9) & 7;
                gl16(Vb0 + (size_t)r * n + j0 + p * 8, smem + 27648 + (size_t)vc * 16);
            }
        }
        __syncthreads();   // staging drained

        // S: wave covers j-cols jg*32 .. +31 (2 tiles), rows mi*16..+15
        #pragma unroll
        for (int u = 0; u < 2; ++u) {
            f32x4 S = zz;
            #pragma unroll
            for (int kk = 0; kk < 64; kk += 32) {
                const bf16x8 af  = *(const bf16x8*)&sQ[mi * 16 + l16][kk + quad * 8];
                const bf16x8 bfr = *(const bf16x8*)&sK[jg * 32 + u * 16 + l16][kk + quad * 8];
                S = __builtin_amdgcn_mfma_f32_16x16x32_bf16(af, bfr, S, 0, 0, 0);
            }
            #pragma unroll
            for (int r = 0; r < 4; ++r) {
                const float e = __expf(S[r] - 32.0f);
                lacc[r] += e;
                sP[mi * 16 + quad * 4 + r][jg * 32 + u * 16 + l16] = f2bf(e);
            }
        }
        __syncthreads();   // P visible

        // PV: wave w -> rows mi*16, channels jg*128 .. +127 (8 tiles)
        #pragma unroll
        for (int kk = 0; kk < 64; kk += 32) {
            const bf16x8 af = *(const bf16x8*)&sP[mi * 16 + l16][kk + quad * 8];
            #pragma unroll
            for (int ct = 0; ct < 8; ++ct) {
                const bf16x8 bfr = *(const bf16x8*)&sV[jg * 128 + ct * 16 + l16][kk + quad * 8];
                acc[ct] = __builtin_amdgcn_mfma_f32_16x16x32_bf16(af, bfr, acc[ct], 0, 0, 0);
            }
        }
    }

    // l reduction: 16 lanes (within quad), then the two jg groups via LDS
    float* sLp = (float*)(smem + 9216);   // [jg][64], aliases sK
    __syncthreads();
    #pragma unroll
    for (int r = 0; r < 4; ++r) {
        float v = lacc[r];
        #pragma unroll
        for (int off = 1; off < 16; off <<= 1) v += __shfl_xor(v, off);
        if (l16 == 0) sLp[jg * 64 + mi * 16 + quad * 4 + r] = v;
    }
    __syncthreads();
    float il[4];
    #pragma unroll
    for (int r = 0; r < 4; ++r) {
        const int row = mi * 16 + quad * 4 + r;
        il[r] = 1.0f / (sLp[row] + sLp[64 + row]);
    }

    // Epilogue: two 128-channel rounds, transpose through LDS (aliases sV)
    const float g = gamma[0];
    float (*sT)[68] = (float(*)[68])(smem + 27648);   // 128 x 68 f32 = 34.8 KB
    #pragma unroll
    for (int h = 0; h < 2; ++h) {
        __syncthreads();
        if (jg == h) {
            #pragma unroll
            for (int ct = 0; ct < 8; ++ct)
                #pragma unroll
                for (int r = 0; r < 4; ++r)
                    sT[ct * 16 + l16][mi * 16 + quad * 4 + r] = acc[ct][r] * il[r];
        }
        __syncthreads();
        #pragma unroll
        for (int u = 0; u < 4; ++u) {
            const int id = u * 512 + t, row = id >> 4, seg = id & 15;
            const size_t gb = ((size_t)b * CH + half * 256 + h * 128 + row) * n + i0 + seg * 4;
            const float4 xv = *(const float4*)&x[gb];
            const float4 ov4 = *(const float4*)&sT[row][seg * 4];
            float4 yv;
            yv.x = g * ov4.x + xv.x;
            yv.y = g * ov4.y + xv.y;
            yv.z = g * ov4.z + xv.z;
            yv.w = g * ov4.w + xv.w;
            *(float4*)&y[gb] = yv;
        }
    }
}

// ---------------------------------------------------------------------------
extern "C" void kernel_launch(void* const* d_in, const int* in_sizes, int n_in,
                              void* d_out, int out_size, void* d_ws, size_t ws_size,
                              hipStream_t stream) {
    const float* x     = (const float*)d_in[0];
    const float* Wq    = (const float*)d_in[1];
    const float* bq    = (const float*)d_in[2];
    const float* Wk    = (const float*)d_in[3];
    const float* bk    = (const float*)d_in[4];
    const float* Wv    = (const float*)d_in[5];
    const float* bv    = (const float*)d_in[6];
    const float* gamma = (const float*)d_in[7];
    float* y = (float*)d_out;

    const int N = 64 * 64;
    const int B = in_sizes[0] / (CH * N);   // = 4

    // ws: q 2.1M | k 2.1M | v2 33.5M | Wcat 0.66M  ~= 38.4 MB
    char* ws = (char*)d_ws;
    short* qB   = (short*)ws;   ws += (size_t)B * N * RED * 2;
    short* kB   = (short*)ws;   ws += (size_t)B * N * RED * 2;
    short* v2   = (short*)ws;   ws += (size_t)B * CH * N * 2;
    short* Wcat = (short*)ws;

    prep_w<<<dim3(640), 256, 0, stream>>>(Wq, Wk, Wv, Wcat);
    qkv_fused<<<dim3(N / 64, 2, B), 256, 0, stream>>>(x, Wcat, bq, bk, bv, qB, kB, v2, N);
    attn_fused512<<<dim3(N / 64, 2, B), 512, 0, stream>>>(qB, kB, v2, x, gamma, y, N);
}